// Round 1
// baseline (209.866 us; speedup 1.0000x reference)
//
#include <hip/hip_runtime.h>
#include <hip/hip_bf16.h>

#define NNODES 50000
#define BKT 64   // bucket capacity; deg ~ Poisson(12.5), P(>64) ~ 1e-38 (clamped)
#define LP 136   // padded bf16 LDS row (272 B = 16*17): b128-aligned, mild bank stagger
#define NXCD 8
#define NPX 6250 // NNODES / NXCD — dst-slice per XCD group

typedef short bf16x8 __attribute__((ext_vector_type(8)));
typedef float f32x4 __attribute__((ext_vector_type(4)));

__device__ __forceinline__ unsigned short f2bf_rn(float f) {
    unsigned int u = __float_as_uint(f);
    return (unsigned short)((u + 0x7fffu + ((u >> 16) & 1u)) >> 16);
}
__device__ __forceinline__ float bf_lo(unsigned int u) { return __uint_as_float(u << 16); }
__device__ __forceinline__ float bf_hi(unsigned int u) { return __uint_as_float(u & 0xffff0000u); }

// ---- k_wt: blocks 0,1 transpose W->bf16 WT[c][k]; blocks 2+ zero cnt ----

__global__ __launch_bounds__(256) void k_wt(const float* __restrict__ W1,
                                            const float* __restrict__ W2,
                                            unsigned short* __restrict__ WT1,
                                            unsigned short* __restrict__ WT2,
                                            int* __restrict__ cnt, int N) {
    __shared__ float tile[128 * 129];
    int b = blockIdx.x, t = threadIdx.x;
    if (b < 2) {
        const float* W = b ? W2 : W1;
        unsigned short* WT = b ? WT2 : WT1;
        for (int idx = t; idx < 128 * 128; idx += 256)
            tile[(idx >> 7) * 129 + (idx & 127)] = W[idx];
        __syncthreads();
        for (int idx = t; idx < 128 * 128; idx += 256) {
            int c = idx >> 7, k = idx & 127;
            WT[c * 128 + k] = f2bf_rn(tile[k * 129 + c]);
        }
    } else {
        int i = (b - 2) * 256 + t;
        if (i < N) cnt[i] = 0;
    }
}

// ---- shared gather-accumulate: 8-deep gathers, int16 indices (int4 = 8 ids) ----
// Adds sum_j rsqrt(cnt[s_j]+1) * xwb_row[s_j] (2 bf16 per lane) into (ax, ay).

__device__ __forceinline__ void gather_accum(const unsigned int* __restrict__ xwb,
                                             const int* __restrict__ cnt,
                                             const unsigned short* __restrict__ bp,
                                             int degc, int lane,
                                             float& ax, float& ay) {
    float px = 0.f, py = 0.f;
    int j = 0;
    for (; j + 8 <= degc; j += 8) {
        int4 q = *(const int4*)&bp[j];  // 8 x u16 ids
        int s0 = q.x & 0xffff, s1 = (int)((unsigned)q.x >> 16);
        int s2 = q.y & 0xffff, s3 = (int)((unsigned)q.y >> 16);
        int s4 = q.z & 0xffff, s5 = (int)((unsigned)q.z >> 16);
        int s6 = q.w & 0xffff, s7 = (int)((unsigned)q.w >> 16);
        unsigned int u0 = xwb[(size_t)s0 * 64 + lane];
        unsigned int u1 = xwb[(size_t)s1 * 64 + lane];
        unsigned int u2 = xwb[(size_t)s2 * 64 + lane];
        unsigned int u3 = xwb[(size_t)s3 * 64 + lane];
        unsigned int u4 = xwb[(size_t)s4 * 64 + lane];
        unsigned int u5 = xwb[(size_t)s5 * 64 + lane];
        unsigned int u6 = xwb[(size_t)s6 * 64 + lane];
        unsigned int u7 = xwb[(size_t)s7 * 64 + lane];
        float w0 = rsqrtf((float)cnt[s0] + 1.0f), w1 = rsqrtf((float)cnt[s1] + 1.0f);
        float w2 = rsqrtf((float)cnt[s2] + 1.0f), w3 = rsqrtf((float)cnt[s3] + 1.0f);
        float w4 = rsqrtf((float)cnt[s4] + 1.0f), w5 = rsqrtf((float)cnt[s5] + 1.0f);
        float w6 = rsqrtf((float)cnt[s6] + 1.0f), w7 = rsqrtf((float)cnt[s7] + 1.0f);
        ax = fmaf(bf_lo(u0), w0, ax);  ay = fmaf(bf_hi(u0), w0, ay);
        px = fmaf(bf_lo(u1), w1, px);  py = fmaf(bf_hi(u1), w1, py);
        ax = fmaf(bf_lo(u2), w2, ax);  ay = fmaf(bf_hi(u2), w2, ay);
        px = fmaf(bf_lo(u3), w3, px);  py = fmaf(bf_hi(u3), w3, py);
        ax = fmaf(bf_lo(u4), w4, ax);  ay = fmaf(bf_hi(u4), w4, ay);
        px = fmaf(bf_lo(u5), w5, px);  py = fmaf(bf_hi(u5), w5, py);
        ax = fmaf(bf_lo(u6), w6, ax);  ay = fmaf(bf_hi(u6), w6, ay);
        px = fmaf(bf_lo(u7), w7, px);  py = fmaf(bf_hi(u7), w7, py);
    }
    if (j + 4 <= degc) {
        int2 q = *(const int2*)&bp[j];  // 4 x u16 ids
        int s0 = q.x & 0xffff, s1 = (int)((unsigned)q.x >> 16);
        int s2 = q.y & 0xffff, s3 = (int)((unsigned)q.y >> 16);
        unsigned int u0 = xwb[(size_t)s0 * 64 + lane];
        unsigned int u1 = xwb[(size_t)s1 * 64 + lane];
        unsigned int u2 = xwb[(size_t)s2 * 64 + lane];
        unsigned int u3 = xwb[(size_t)s3 * 64 + lane];
        float w0 = rsqrtf((float)cnt[s0] + 1.0f), w1 = rsqrtf((float)cnt[s1] + 1.0f);
        float w2 = rsqrtf((float)cnt[s2] + 1.0f), w3 = rsqrtf((float)cnt[s3] + 1.0f);
        ax = fmaf(bf_lo(u0), w0, ax);  ay = fmaf(bf_hi(u0), w0, ay);
        px = fmaf(bf_lo(u1), w1, px);  py = fmaf(bf_hi(u1), w1, py);
        ax = fmaf(bf_lo(u2), w2, ax);  ay = fmaf(bf_hi(u2), w2, ay);
        px = fmaf(bf_lo(u3), w3, px);  py = fmaf(bf_hi(u3), w3, py);
        j += 4;
    }
    for (; j < degc; ++j) {
        int s = bp[j];
        float wv = rsqrtf((float)cnt[s] + 1.0f);
        unsigned int u = xwb[(size_t)s * 64 + lane];
        ax = fmaf(bf_lo(u), wv, ax);
        ay = fmaf(bf_hi(u), wv, ay);
    }
    ax += px;
    ay += py;
}

// ---- merged: gemm1 (blocks >= EBTOT) + XCD-sliced bucket build (blocks < EBTOT) ----
// bucket: blockIdx%8 group owns dst slice [g*NPX, g*NPX+NPX); group rescans all dsts
// (int4 loads, L3-absorbed) and processes only its hits -> all atomics + bucket-line
// writes for a node come from ONE XCD; slice (0.8 MB u16) stays L2-resident, single
// write-back at kernel end instead of ~7 cross-XCD evictions per line.
// gemm: Yb[n,128](bf16) = X[n,128] @ W1; B fragments read direct from L1/L2-resident
// WT (no LDS W stage) -> LDS 17.4 KB epilogue-only -> 8 blocks/CU (thread-capped).

__global__ __launch_bounds__(256) void k_gemmbucket(const float* __restrict__ X,
                                                    const unsigned short* __restrict__ WT,
                                                    unsigned short* __restrict__ Yb, int n,
                                                    const int* __restrict__ src,
                                                    const int* __restrict__ dst,
                                                    int* __restrict__ cnt,
                                                    unsigned short* __restrict__ bkt,
                                                    int E, int EBTOT) {
    __shared__ unsigned short Ep[64 * LP];  // 17.4 KB: epilogue tile only
    int t = threadIdx.x;
    if ((int)blockIdx.x < EBTOT) {  // ---- bucket role ----
        int g = blockIdx.x & (NXCD - 1);  // round-robin dispatch -> stable XCD per g
        int kk = blockIdx.x >> 3;
        int lo = g * NPX;
        int SLOTS = E >> 2;
        int idx = kk * 256 + t;
        if (idx < SLOTS) {
            int4 d4 = ((const int4*)dst)[idx];
            int e0 = idx << 2;
            if ((unsigned)(d4.x - lo) < (unsigned)NPX) {
                int pos = atomicAdd(&cnt[d4.x], 1);
                if (pos < BKT) bkt[(size_t)d4.x * BKT + pos] = (unsigned short)src[e0];
            }
            if ((unsigned)(d4.y - lo) < (unsigned)NPX) {
                int pos = atomicAdd(&cnt[d4.y], 1);
                if (pos < BKT) bkt[(size_t)d4.y * BKT + pos] = (unsigned short)src[e0 + 1];
            }
            if ((unsigned)(d4.z - lo) < (unsigned)NPX) {
                int pos = atomicAdd(&cnt[d4.z], 1);
                if (pos < BKT) bkt[(size_t)d4.z * BKT + pos] = (unsigned short)src[e0 + 2];
            }
            if ((unsigned)(d4.w - lo) < (unsigned)NPX) {
                int pos = atomicAdd(&cnt[d4.w], 1);
                if (pos < BKT) bkt[(size_t)d4.w * BKT + pos] = (unsigned short)src[e0 + 3];
            }
        }
        if (kk == 0 && t < (E & 3)) {  // E%4 tail (0 for this problem, kept for safety)
            int e = (E & ~3) + t;
            int d = dst[e];
            if ((unsigned)(d - lo) < (unsigned)NPX) {
                int pos = atomicAdd(&cnt[d], 1);
                if (pos < BKT) bkt[(size_t)d * BKT + pos] = (unsigned short)src[e];
            }
        }
        return;
    }
    // ---- gemm role ----
    int gb = blockIdx.x - EBTOT;
    int lane = t & 63, w = t >> 6;
    int m = lane & 15, quad = lane >> 4;
    int base = gb * 64 + w * 16;
    int row = min(base + m, n - 1);  // duplicate-row tail; stores guarded

    bf16x8 a[4];
#pragma unroll
    for (int kt = 0; kt < 4; ++kt) {
        const float* pa = &X[(size_t)row * 128 + kt * 32 + quad * 8];
        float4 v0 = *(const float4*)pa;
        float4 v1 = *(const float4*)(pa + 4);
        a[kt][0] = (short)f2bf_rn(v0.x); a[kt][1] = (short)f2bf_rn(v0.y);
        a[kt][2] = (short)f2bf_rn(v0.z); a[kt][3] = (short)f2bf_rn(v0.w);
        a[kt][4] = (short)f2bf_rn(v1.x); a[kt][5] = (short)f2bf_rn(v1.y);
        a[kt][6] = (short)f2bf_rn(v1.z); a[kt][7] = (short)f2bf_rn(v1.w);
    }

    f32x4 acc[8];
#pragma unroll
    for (int i = 0; i < 8; ++i) acc[i] = f32x4{0.f, 0.f, 0.f, 0.f};
#pragma unroll
    for (int kt = 0; kt < 4; ++kt) {
        int ko = kt * 32 + quad * 8;
#pragma unroll
        for (int ct = 0; ct < 8; ++ct) {
            bf16x8 b = *(const bf16x8*)&WT[(ct * 16 + m) * 128 + ko];  // L1/L2-resident
            acc[ct] = __builtin_amdgcn_mfma_f32_16x16x32_bf16(a[kt], b, acc[ct], 0, 0, 0);
        }
    }

    unsigned short* ep = &Ep[w * 16 * LP];
#pragma unroll
    for (int ct = 0; ct < 8; ++ct)
#pragma unroll
        for (int r = 0; r < 4; ++r)
            ep[(quad * 4 + r) * LP + ct * 16 + m] = f2bf_rn(acc[ct][r]);
    __syncthreads();
    int rr = lane & 15, cc = lane >> 4;
    int orow = base + rr;
    if (orow < n) {
#pragma unroll
        for (int i2 = 0; i2 < 4; ++i2)
            ((uint4*)&Yb[(size_t)orow * 128])[cc * 4 + i2] =
                *(const uint4*)&ep[rr * LP + (cc * 4 + i2) * 8];
    }
}

// ---- fused agg(layer1)+gemm2: 16 waves, one node per wave (MLP preserved) ----
// h_row(bf16, LDS) = relu(di*(sum + di*x_i) + b1); then xw2 = h @ W2 (bf16 out).

__global__ __launch_bounds__(1024, 2) void k_aggemm(const unsigned int* __restrict__ xw1,
                                                    const int* __restrict__ cnt,
                                                    const unsigned short* __restrict__ bkt,
                                                    const float* __restrict__ bias,
                                                    const unsigned short* __restrict__ WT2,
                                                    unsigned short* __restrict__ xw2, int n) {
    __shared__ unsigned short Wl[128 * LP];  // 34 KB
    __shared__ unsigned short At[16 * LP];   // 4.25 KB: h tile, then output tile
    int t = threadIdx.x, lane = t & 63, w = t >> 6;
    int base = blockIdx.x * 16;

    // stage W2 (all 16 waves cooperate)
    for (int idx = t; idx < 128 * 16; idx += 1024) {
        int r = idx >> 4, c8 = (idx & 15) << 3;
        *(uint4*)&Wl[r * LP + c8] = *(const uint4*)&WT2[r * 128 + c8];
    }

    // aggregate: node i = base + w, one node per wave
    int i = min(base + w, n - 1);
    int deg = cnt[i];
    int degc = min(deg, BKT);
    float di = rsqrtf((float)deg + 1.0f);
    unsigned int v0 = xw1[(size_t)i * 64 + lane];
    float ax = di * bf_lo(v0), ay = di * bf_hi(v0);
    gather_accum(xw1, cnt, &bkt[(size_t)i * BKT], degc, lane, ax, ay);
    float bx = bias[lane * 2], by = bias[lane * 2 + 1];
    ax = fmaxf(fmaf(di, ax, bx), 0.0f);
    ay = fmaxf(fmaf(di, ay, by), 0.0f);
    ((unsigned int*)&At[w * LP])[lane] = (unsigned)f2bf_rn(ax) | ((unsigned)f2bf_rn(ay) << 16);
    __syncthreads();

    // gemm2 on the 16x128 tile: waves 0-7, col-tile ct = w
    int m = lane & 15, quad = lane >> 4;
    f32x4 acc = f32x4{0.f, 0.f, 0.f, 0.f};
    if (w < 8) {
        bf16x8 a[4];
#pragma unroll
        for (int kt = 0; kt < 4; ++kt)
            a[kt] = *(const bf16x8*)&At[m * LP + kt * 32 + quad * 8];
#pragma unroll
        for (int kt = 0; kt < 4; ++kt) {
            bf16x8 b = *(const bf16x8*)&Wl[(w * 16 + m) * LP + kt * 32 + quad * 8];
            acc = __builtin_amdgcn_mfma_f32_16x16x32_bf16(a[kt], b, acc, 0, 0, 0);
        }
    }
    __syncthreads();  // A reads done; overwrite At with output tile
    if (w < 8) {
#pragma unroll
        for (int r = 0; r < 4; ++r)
            At[(quad * 4 + r) * LP + w * 16 + m] = f2bf_rn(acc[r]);
    }
    __syncthreads();
    if (t < 256) {  // store 16 rows x 128 cols (uint4 per thread-slot)
        int row = t >> 4, q = t & 15;
        int orow = base + row;
        if (orow < n)
            *(uint4*)&xw2[(size_t)orow * 128 + q * 8] = *(const uint4*)&At[row * LP + q * 8];
    }
}

// ---- final aggregate (layer 2), fp32 out ----

__global__ __launch_bounds__(256) void k_agg(const unsigned int* __restrict__ xwb,
                                             const int* __restrict__ cnt,
                                             const unsigned short* __restrict__ bkt,
                                             const float* __restrict__ bias,
                                             float* __restrict__ out, int n) {
    int lane = threadIdx.x & 63;
    int i = (blockIdx.x * 256 + threadIdx.x) >> 6;  // one wave per node
    if (i >= n) return;
    int deg = cnt[i];
    int degc = min(deg, BKT);
    float di = rsqrtf((float)deg + 1.0f);
    unsigned int v0 = xwb[(size_t)i * 64 + lane];
    float ax = di * bf_lo(v0), ay = di * bf_hi(v0);
    gather_accum(xwb, cnt, &bkt[(size_t)i * BKT], degc, lane, ax, ay);
    float bx = bias[lane * 2], by = bias[lane * 2 + 1];
    ax = fmaxf(fmaf(di, ax, bx), 0.0f);
    ay = fmaxf(fmaf(di, ay, by), 0.0f);
    ((float2*)out)[(size_t)i * 64 + lane] = make_float2(ax, ay);
}

// ---------------- launch ----------------

extern "C" void kernel_launch(void* const* d_in, const int* in_sizes, int n_in,
                              void* d_out, int out_size, void* d_ws, size_t ws_size,
                              hipStream_t stream) {
    const float* x  = (const float*)d_in[0];
    const int*   ei = (const int*)d_in[1];
    const float* W1 = (const float*)d_in[2];
    const float* b1 = (const float*)d_in[3];
    const float* W2 = (const float*)d_in[4];
    const float* b2 = (const float*)d_in[5];
    float* out = (float*)d_out;

    const int N = NNODES;
    const int E = in_sizes[1] / 2;  // 625000
    const int* src = ei;
    const int* dst = ei + E;

    char* p = (char*)d_ws;
    size_t off = 0;
    auto take = [&](size_t bytes) -> void* {
        void* r = p + off;
        off = (off + bytes + 255) & ~(size_t)255;
        return r;
    };
    int* cnt = (int*)take((size_t)N * 4);
    unsigned short* bkt = (unsigned short*)take((size_t)N * BKT * 2);  // 6.4 MB u16
    unsigned short* w1t = (unsigned short*)take(128 * 128 * 2);
    unsigned short* w2t = (unsigned short*)take(128 * 128 * 2);
    unsigned short* xw1 = (unsigned short*)take((size_t)N * 128 * 2);  // bf16 x@W1
    unsigned short* xw2 = (unsigned short*)take((size_t)N * 128 * 2);  // bf16 h@W2

    const int NB = (N + 255) / 256;          // cnt-zero blocks
    const int SLOTS = E / 4;                 // 156250 int4 dst slots
    const int NBG = (SLOTS + 255) / 256;     // 611 blocks per XCD group
    const int EBTOT = NBG * NXCD;            // 4888 bucket blocks
    const int GB = (N + 63) / 64;            // 782 gemm blocks

    // 1: W transposes + cnt zero
    k_wt<<<2 + NB, 256, 0, stream>>>(W1, W2, w1t, w2t, cnt, N);
    // 2: XCD-sliced bucket build overlapped with gemm1 (disjoint inputs)
    k_gemmbucket<<<EBTOT + GB, 256, 0, stream>>>(x, w1t, xw1, N, src, dst, cnt, bkt, E, EBTOT);
    // 3: fused agg(layer1)+bias+relu+gemm2
    k_aggemm<<<(N + 15) / 16, 1024, 0, stream>>>((const unsigned int*)xw1, cnt, bkt,
                                                 b1, w2t, xw2, N);
    // 4: final aggregate + bias + relu (fp32 out)
    k_agg<<<(N * 64 + 255) / 256, 256, 0, stream>>>((const unsigned int*)xw2, cnt, bkt,
                                                    b2, out, N);
}